// Round 10
// baseline (70.495 us; speedup 1.0000x reference)
//
#include <hip/hip_runtime.h>

// Chamfer via MFMA, atomic-light, single compute kernel.
// d2 = psq + qsq - 2 p.q in ONE v_mfma_f32_32x32x16_bf16 per 32x32 tile
// (packing PROVEN R6-R9, absmax 0.0):
//   A k: {psqh,psql,-2ph(y,z,w),-2pl(y,z,w) | -2ph(y,z,w),1,1,0,0,0}
//   B k: {1,1,qh(y,z,w),qh(y,z,w) | ql(y,z,w),qsqh,qsql,0,0,0}
// Two dir-passes over tile space. Inner loop: NO reductions — col-partial
// mins accumulate ELEMENTWISE in C layout; 2 row-tiles x 4 col-tiles per
// step (8 independent MFMAs per 2 LDS A-reads; min3 folds = 8 VALU/tile).
// Epilogue: 16->1 tree, shfl_xor(32), sqrt, wave+block sum, one atomicAdd.
// Grid: 128 batches x 2 dirs x 2 col-halves = 512 blocks x 256 thr
// (4 waves x 4 col-tiles each = 512 cols/block). LDS 48 KB -> 2 blocks/CU.
// out zeroed by a 4-byte memset dispatch (atomic accumulation target).

typedef short bf16x8 __attribute__((ext_vector_type(8)));
typedef float f32x16 __attribute__((ext_vector_type(16)));

#define ONE_BF 0x3f80

__device__ __forceinline__ unsigned short f2bf(float x) {
    unsigned u = __float_as_uint(x);
    u += 0x7fffu + ((u >> 16) & 1u);          // round-to-nearest-even
    return (unsigned short)(u >> 16);
}
__device__ __forceinline__ float bf2f(unsigned short h) {
    return __uint_as_float(((unsigned)h) << 16);
}

__global__ __launch_bounds__(256, 2) void chamfer_dir(
    const float4* __restrict__ P, const float4* __restrict__ Q,
    float* __restrict__ out)
{
    __shared__ short lAh[1024 * 8];   // A k-slots 0-7  (16 KB)
    __shared__ short lAl[1024 * 8];   // A k-slots 8-15 (16 KB)
    __shared__ short lB[512 * 16];    // B interleaved [pt][half][8] (16 KB)
    __shared__ float wsum[4];

    const int blk   = blockIdx.x;
    const int batch = blk >> 2;        // 0..127
    const int dir   = (blk >> 1) & 1;  // 0: rows=P cols=Q; 1: swapped
    const int cb    = blk & 1;         // col-half (512 cols each)
    const int t     = threadIdx.x;
    const int base  = batch << 10;

    const float4* __restrict__ ownb = (dir ? Q : P) + base;   // rows
    const float4* __restrict__ oppb = (dir ? P : Q) + base;   // cols

    // ---- Pack rows (full cloud) into LDS A-fragments: 4 pts/thread ----
#pragma unroll
    for (int i = 0; i < 4; ++i) {
        const int pt = t + (i << 8);
        float4 v = ownb[pt];
        float psq = v.y * v.y + v.z * v.z + v.w * v.w;
        unsigned short psqh = f2bf(psq);
        unsigned short psql = f2bf(psq - bf2f(psqh));
        unsigned short yh = f2bf(v.y), zh = f2bf(v.z), wh = f2bf(v.w);
        unsigned short m2yh = f2bf(-2.0f * bf2f(yh));
        unsigned short m2zh = f2bf(-2.0f * bf2f(zh));
        unsigned short m2wh = f2bf(-2.0f * bf2f(wh));
        unsigned short m2yl = f2bf(-2.0f * (v.y - bf2f(yh)));
        unsigned short m2zl = f2bf(-2.0f * (v.z - bf2f(zh)));
        unsigned short m2wl = f2bf(-2.0f * (v.w - bf2f(wh)));
        bf16x8 ah = { (short)psqh, (short)psql, (short)m2yh, (short)m2zh,
                      (short)m2wh, (short)m2yl, (short)m2zl, (short)m2wl };
        bf16x8 al = { (short)m2yh, (short)m2zh, (short)m2wh,
                      (short)ONE_BF, (short)ONE_BF, 0, 0, 0 };
        *(bf16x8*)&lAh[pt * 8] = ah;
        *(bf16x8*)&lAl[pt * 8] = al;
    }
    // ---- Pack this block's 512 cols into LDS B-fragments: 2 pts/thread ----
#pragma unroll
    for (int i = 0; i < 2; ++i) {
        const int pt = t + (i << 8);              // local col 0..511
        float4 v = oppb[(cb << 9) + pt];
        float qsq = v.y * v.y + v.z * v.z + v.w * v.w;
        unsigned short qsqh = f2bf(qsq);
        unsigned short qsql = f2bf(qsq - bf2f(qsqh));
        unsigned short yh = f2bf(v.y), zh = f2bf(v.z), wh = f2bf(v.w);
        unsigned short yl = f2bf(v.y - bf2f(yh));
        unsigned short zl = f2bf(v.z - bf2f(zh));
        unsigned short wl = f2bf(v.w - bf2f(wh));
        bf16x8 bh = { (short)ONE_BF, (short)ONE_BF, (short)yh, (short)zh,
                      (short)wh, (short)yh, (short)zh, (short)wh };
        bf16x8 bl = { (short)yl, (short)zl, (short)wl,
                      (short)qsqh, (short)qsql, 0, 0, 0 };
        *(bf16x8*)&lB[pt * 16]     = bh;
        *(bf16x8*)&lB[pt * 16 + 8] = bl;
    }
    __syncthreads();

    const int lane = t & 63;
    const int half = lane >> 5;    // k-half: 0 -> slots 0-7, 1 -> 8-15
    const int l31  = lane & 31;
    const int wv   = t >> 6;

    const short* aptr = half ? lAl : lAh;

    // Four local col-tiles per wave: ct = wv*4 + k  (local cols wv*128+...)
    bf16x8 bf[4];
#pragma unroll
    for (int k = 0; k < 4; ++k) {
        const int pt = ((wv << 2) + k) * 32 + l31;
        bf[k] = *(const bf16x8*)&lB[(pt * 2 + half) * 8];
    }

    f32x16 zf;
#pragma unroll
    for (int j = 0; j < 16; ++j) zf[j] = 0.0f;

    f32x16 acc[4];
#pragma unroll
    for (int k = 0; k < 4; ++k)
#pragma unroll
        for (int j = 0; j < 16; ++j) acc[k][j] = 3.4e38f;

    // Inner: 2 row-tiles x 4 col-tiles per step, elementwise min3 folds.
    for (int rt = 0; rt < 32; rt += 2) {
        bf16x8 af0 = *(const bf16x8*)&aptr[((rt << 5) + l31) * 8];
        bf16x8 af1 = *(const bf16x8*)&aptr[(((rt + 1) << 5) + l31) * 8];
#pragma unroll
        for (int k = 0; k < 4; ++k) {
            f32x16 ca = __builtin_amdgcn_mfma_f32_32x32x16_bf16(af0, bf[k], zf, 0, 0, 0);
            f32x16 cb2 = __builtin_amdgcn_mfma_f32_32x32x16_bf16(af1, bf[k], zf, 0, 0, 0);
#pragma unroll
            for (int j = 0; j < 16; ++j)
                acc[k][j] = fminf(fminf(ca[j], cb2[j]), acc[k][j]);  // v_min3
        }
    }

    // Epilogue: 16->1 tree per col-tile, cross-half shfl, sqrt, sums.
    float s = 0.0f;
#pragma unroll
    for (int k = 0; k < 4; ++k) {
        float m = acc[k][0];
#pragma unroll
        for (int j = 1; j < 16; ++j) m = fminf(m, acc[k][j]);
        m = fminf(m, __shfl_xor(m, 32, 64));
        if (half == 0) s += sqrtf(fmaxf(m, 0.0f) + 1e-12f);
    }
#pragma unroll
    for (int off = 32; off; off >>= 1) s += __shfl_down(s, off, 64);
    if (lane == 0) wsum[wv] = s;
    __syncthreads();
    if (t == 0) atomicAdd(out, wsum[0] + wsum[1] + wsum[2] + wsum[3]);
}

extern "C" void kernel_launch(void* const* d_in, const int* in_sizes, int n_in,
                              void* d_out, int out_size, void* d_ws, size_t ws_size,
                              hipStream_t stream) {
    const float4* P = (const float4*)d_in[0];
    const float4* Q = (const float4*)d_in[1];
    float* out = (float*)d_out;

    hipMemsetAsync(d_out, 0, sizeof(float), stream);
    chamfer_dir<<<dim3(128 * 2 * 2), dim3(256), 0, stream>>>(P, Q, out);
}